// Round 1
// baseline (433.477 us; speedup 1.0000x reference)
//
#include <hip/hip_runtime.h>
#include <math.h>

typedef unsigned short us;
typedef short bf16x8 __attribute__((ext_vector_type(8)));
typedef float f32x4 __attribute__((ext_vector_type(4)));

#define LQ 384
#define DPAIR 128
#define KDIM 12288  // L*32

// ws byte offsets
#define WT_OFF   0UL
#define Q_OFF    262144UL
#define K_OFF    38010880UL
#define V_OFF    75759616UL
#define G_OFF    113508352UL
#define ATT_OFF  151257088UL
#define LOG_OFF  152436736UL
// O reuses Q's slot (Q dead after k_logits)

__device__ __forceinline__ us f2bf(float x){
  unsigned u = __builtin_bit_cast(unsigned, x);
  return (us)((u + 0x7FFFu + ((u >> 16) & 1u)) >> 16);
}
__device__ __forceinline__ float bf2f(us b){
  unsigned u = ((unsigned)b) << 16;
  return __builtin_bit_cast(float, u);
}
__device__ __forceinline__ void gl_lds16(const void* g, void* l){
  __builtin_amdgcn_global_load_lds((const __attribute__((address_space(1))) unsigned*)g,
                                   (__attribute__((address_space(3))) unsigned*)l, 16, 0, 0);
}
__device__ __forceinline__ float wsum(float x){
  #pragma unroll
  for (int o = 32; o; o >>= 1) x += __shfl_xor(x, o, 64);
  return x;
}
__device__ __forceinline__ float wmaxr(float x){
  #pragma unroll
  for (int o = 32; o; o >>= 1) x = fmaxf(x, __shfl_xor(x, o, 64));
  return x;
}

// ---------------- K0: pack transposed bf16 weights (scalings folded) ----------------
__global__ __launch_bounds__(256) void k_pack(
    const float* __restrict__ Wq, const float* __restrict__ Wk,
    const float* __restrict__ Wv, const float* __restrict__ Wg,
    const float* __restrict__ Wo, us* __restrict__ wt)
{
  int idx = blockIdx.x * 256 + threadIdx.x;       // < 5*16384
  int m = idx >> 14, rr = idx & 16383, n = rr >> 7, k = rr & 127;
  const float* W; float s;
  switch (m) {
    case 0: W = Wq; s = 0.17677669529663687f; break;   // 1/sqrt(32)
    case 1: W = Wk; s = 0.05103103630798287f; break;   // 1/sqrt(384)
    case 2: W = Wv; s = 1.f; break;
    case 3: W = Wg; s = 1.f; break;
    default: W = Wo; s = 1.f; break;
  }
  wt[idx] = f2bf(W[k * 128 + n] * s);                  // WT[n][k] = W[k][n]*s
}

// ---------------- K1: LayerNorm + q/k/v/g projections ----------------
// p row (a,b) = LN(pair[b,a,:]).  Block: fixed a, 64 rows b0..b0+63, 4 waves.
// wave0 -> Q[h][b][a*32+c], wave1 -> K[h][b][a*32+c],
// wave2 -> V[h][a*32+d][b], wave3 -> G[a][b][hd] (sigmoid(x+bg))
__global__ __launch_bounds__(256) void k_ln_qkvg(
    const float* __restrict__ pair, const float* __restrict__ lng,
    const float* __restrict__ lnb, const float* __restrict__ bg,
    const us* __restrict__ wt,
    us* __restrict__ Qw, us* __restrict__ Kw, us* __restrict__ Vw, us* __restrict__ Gw)
{
  __shared__ __attribute__((aligned(16))) us p_lds[64 * 128];
  __shared__ __attribute__((aligned(16))) us stg[4][3208];
  const int tid = threadIdx.x, w = tid >> 6, l = tid & 63;
  const int a = blockIdx.x / 6, b0 = (blockIdx.x % 6) * 64;
  const float g0 = lng[l], g1 = lng[l + 64], bb0 = lnb[l], bb1 = lnb[l + 64];
  #pragma unroll
  for (int rr = 0; rr < 16; ++rr) {
    const int m = w * 16 + rr;
    const float* src = pair + ((size_t)(b0 + m) * LQ + a) * DPAIR;
    float x0 = src[l], x1 = src[l + 64];
    float mu  = wsum(x0 + x1) * (1.f / 128.f);
    float var = wsum(x0 * x0 + x1 * x1) * (1.f / 128.f) - mu * mu;
    float rstd = rsqrtf(var + 1e-5f);
    float y0 = (x0 - mu) * rstd * g0 + bb0;
    float y1 = (x1 - mu) * rstd * g1 + bb1;
    int c0 = (l >> 3) ^ (m & 7);
    int c1 = ((l + 64) >> 3) ^ (m & 7);
    p_lds[m * 128 + c0 * 8 + (l & 7)] = f2bf(y0);
    p_lds[m * 128 + c1 * 8 + (l & 7)] = f2bf(y1);
  }
  __syncthreads();
  const us* W = wt + w * 16384;
  f32x4 acc[4][8];
  #pragma unroll
  for (int mt = 0; mt < 4; ++mt)
    #pragma unroll
    for (int nt = 0; nt < 8; ++nt) acc[mt][nt] = (f32x4){0.f, 0.f, 0.f, 0.f};
  const int row16 = l & 15, kq = l >> 4;
  #pragma unroll
  for (int kb = 0; kb < 4; ++kb) {
    bf16x8 af[4], bv[8];
    #pragma unroll
    for (int mt = 0; mt < 4; ++mt) {
      int r = mt * 16 + row16;
      int c = (kb * 4 + kq) ^ (r & 7);
      af[mt] = *(const bf16x8*)&p_lds[r * 128 + c * 8];
    }
    #pragma unroll
    for (int nt = 0; nt < 8; ++nt)
      bv[nt] = *(const bf16x8*)&W[(nt * 16 + row16) * 128 + kb * 32 + kq * 8];
    #pragma unroll
    for (int mt = 0; mt < 4; ++mt)
      #pragma unroll
      for (int nt = 0; nt < 8; ++nt)
        acc[mt][nt] = __builtin_amdgcn_mfma_f32_16x16x32_bf16(af[mt], bv[nt], acc[mt][nt], 0, 0, 0);
  }
  // epilogue: per-head LDS staging, coalesced 16B stores
  us* st = stg[w];
  #pragma unroll
  for (int hh = 0; hh < 4; ++hh) {
    if (w == 2) {
      // transposed stage [32 d][stride 72]
      #pragma unroll
      for (int nf = 0; nf < 2; ++nf) {
        int d = nf * 16 + row16;
        #pragma unroll
        for (int mt = 0; mt < 4; ++mt) {
          f32x4 vv = acc[mt][2 * hh + nf];
          #pragma unroll
          for (int v4 = 0; v4 < 4; ++v4)
            st[d * 72 + mt * 16 + kq * 4 + v4] = f2bf(vv[v4]);
        }
      }
      asm volatile("s_waitcnt lgkmcnt(0)" ::: "memory");
      #pragma unroll
      for (int it = 0; it < 4; ++it) {
        int d = (l >> 3) + it * 8;
        int mm = l & 7;
        bf16x8 val = *(const bf16x8*)&st[d * 72 + mm * 8];
        *(bf16x8*)&Vw[((size_t)hh * KDIM + a * 32 + d) * LQ + b0 + mm * 8] = val;
      }
      asm volatile("s_waitcnt lgkmcnt(0)" ::: "memory");
    } else {
      // row-major stage [64 m][stride 40]
      #pragma unroll
      for (int nf = 0; nf < 2; ++nf) {
        int cc = nf * 16 + row16;
        float bgv = (w == 3) ? bg[hh * 32 + cc] : 0.f;
        #pragma unroll
        for (int mt = 0; mt < 4; ++mt) {
          f32x4 vv = acc[mt][2 * hh + nf];
          #pragma unroll
          for (int v4 = 0; v4 < 4; ++v4) {
            float x = vv[v4];
            if (w == 3) x = 1.f / (1.f + expf(-(x + bgv)));
            st[(mt * 16 + kq * 4 + v4) * 40 + cc] = f2bf(x);
          }
        }
      }
      asm volatile("s_waitcnt lgkmcnt(0)" ::: "memory");
      #pragma unroll
      for (int it = 0; it < 4; ++it) {
        int mrow = (l >> 2) + it * 16;
        int c8 = l & 3;
        bf16x8 val = *(const bf16x8*)&st[mrow * 40 + c8 * 8];
        if (w == 0)
          *(bf16x8*)&Qw[((size_t)hh * LQ + b0 + mrow) * KDIM + a * 32 + c8 * 8] = val;
        else if (w == 1)
          *(bf16x8*)&Kw[((size_t)hh * LQ + b0 + mrow) * KDIM + a * 32 + c8 * 8] = val;
        else
          *(bf16x8*)&Gw[((size_t)a * LQ + b0 + mrow) * DPAIR + hh * 32 + c8 * 8] = val;
      }
      asm volatile("s_waitcnt lgkmcnt(0)" ::: "memory");
    }
  }
}

// ---------------- K2: logits GEMM (K-split 8, atomicAdd fp32) ----------------
__global__ __launch_bounds__(256) void k_logits(
    const us* __restrict__ Qw, const us* __restrict__ Kw, float* __restrict__ logits)
{
  __shared__ __attribute__((aligned(16))) us AB[2][128 * 64];
  const int tid = threadIdx.x, w = tid >> 6, l = tid & 63;
  const int bx = blockIdx.x;
  const int h = bx / 72, r2 = bx % 72, ks = r2 / 9, t = r2 % 9;
  const int i0 = (t / 3) * 128, j0 = (t % 3) * 128;
  const us* Ab = Qw + (size_t)h * LQ * KDIM;
  const us* Bb = Kw + (size_t)h * LQ * KDIM;
  f32x4 acc[4][4];
  #pragma unroll
  for (int mt = 0; mt < 4; ++mt)
    #pragma unroll
    for (int nt = 0; nt < 4; ++nt) acc[mt][nt] = (f32x4){0.f, 0.f, 0.f, 0.f};
  const int m0 = (w & 1) * 64, n0 = (w >> 1) * 64;
  const int row16 = l & 15, kq = l >> 4;
  for (int kk = 0; kk < 24; ++kk) {
    const int koff = ks * 1536 + kk * 64;
    #pragma unroll
    for (int s = 0; s < 4; ++s) {
      int slot = (s * 4 + w) * 64 + l;
      int rrow = slot >> 3, cc = slot & 7;
      int cg = cc ^ (rrow & 7);
      gl_lds16(Ab + (size_t)(i0 + rrow) * KDIM + koff + cg * 8, &AB[0][slot * 8]);
      gl_lds16(Bb + (size_t)(j0 + rrow) * KDIM + koff + cg * 8, &AB[1][slot * 8]);
    }
    asm volatile("s_waitcnt vmcnt(0)" ::: "memory");
    __syncthreads();
    #pragma unroll
    for (int kb = 0; kb < 2; ++kb) {
      bf16x8 af[4], bv[4];
      #pragma unroll
      for (int mt = 0; mt < 4; ++mt) {
        int r = m0 + mt * 16 + row16;
        int c = (kb * 4 + kq) ^ (r & 7);
        af[mt] = *(const bf16x8*)&AB[0][r * 64 + c * 8];
      }
      #pragma unroll
      for (int nt = 0; nt < 4; ++nt) {
        int r = n0 + nt * 16 + row16;
        int c = (kb * 4 + kq) ^ (r & 7);
        bv[nt] = *(const bf16x8*)&AB[1][r * 64 + c * 8];
      }
      #pragma unroll
      for (int mt = 0; mt < 4; ++mt)
        #pragma unroll
        for (int nt = 0; nt < 4; ++nt)
          acc[mt][nt] = __builtin_amdgcn_mfma_f32_16x16x32_bf16(af[mt], bv[nt], acc[mt][nt], 0, 0, 0);
    }
    __syncthreads();
  }
  #pragma unroll
  for (int mt = 0; mt < 4; ++mt)
    #pragma unroll
    for (int nt = 0; nt < 4; ++nt)
      #pragma unroll
      for (int v4 = 0; v4 < 4; ++v4) {
        int i = i0 + m0 + mt * 16 + kq * 4 + v4;
        int j = j0 + n0 + nt * 16 + row16;
        atomicAdd(&logits[((size_t)h * LQ + i) * LQ + j], acc[mt][nt][v4]);
      }
}

// ---------------- K3: bias@Wb + softmax over j ----------------
__global__ __launch_bounds__(256) void k_softmax(
    const float* __restrict__ bias, const float* __restrict__ Wb,
    const float* __restrict__ logits, us* __restrict__ attn)
{
  __shared__ float bp[4][LQ];
  const int tid = threadIdx.x, w = tid >> 6, l = tid & 63;
  const int i = blockIdx.x;
  const float4* Wb4 = (const float4*)Wb;          // Wb row = float4
  const float4 w0 = Wb4[l], w1 = Wb4[l + 64];
  for (int jt = 0; jt < 96; ++jt) {
    int j = jt * 4 + w;
    const float* br = bias + ((size_t)i * LQ + j) * DPAIR;
    float bv0 = br[l], bv1 = br[l + 64];
    float p0 = bv0 * w0.x + bv1 * w1.x;
    float p1 = bv0 * w0.y + bv1 * w1.y;
    float p2 = bv0 * w0.z + bv1 * w1.z;
    float p3 = bv0 * w0.w + bv1 * w1.w;
    #pragma unroll
    for (int o = 32; o; o >>= 1) {
      p0 += __shfl_xor(p0, o, 64);
      p1 += __shfl_xor(p1, o, 64);
      p2 += __shfl_xor(p2, o, 64);
      p3 += __shfl_xor(p3, o, 64);
    }
    if (l == 0) { bp[0][j] = p0; bp[1][j] = p1; bp[2][j] = p2; bp[3][j] = p3; }
  }
  __syncthreads();
  const int h = w;
  const float* lrow = logits + ((size_t)h * LQ + i) * LQ;
  float x[6];
  #pragma unroll
  for (int s = 0; s < 6; ++s) x[s] = lrow[l + 64 * s] + bp[h][l + 64 * s];
  float mx = x[0];
  #pragma unroll
  for (int s = 1; s < 6; ++s) mx = fmaxf(mx, x[s]);
  mx = wmaxr(mx);
  float e[6], sum = 0.f;
  #pragma unroll
  for (int s = 0; s < 6; ++s) { e[s] = expf(x[s] - mx); sum += e[s]; }
  sum = wsum(sum);
  float rinv = 1.f / sum;
  #pragma unroll
  for (int s = 0; s < 6; ++s)
    attn[((size_t)h * LQ + i) * LQ + l + 64 * s] = f2bf(e[s] * rinv);
}

// ---------------- K4: o = attn @ V^T per head ----------------
__global__ __launch_bounds__(256) void k_ogemm(
    const us* __restrict__ attn, const us* __restrict__ Vw, us* __restrict__ Ow)
{
  __shared__ __attribute__((aligned(16))) us AB[2][128 * 64];
  const int tid = threadIdx.x, w = tid >> 6, l = tid & 63;
  const int bx = blockIdx.x;
  const int h = bx / 288, r2 = bx % 288;
  const int i0 = (r2 / 96) * 128, n0 = (r2 % 96) * 128;
  const us* Ab = attn + (size_t)h * LQ * LQ;
  const us* Bb = Vw + (size_t)h * KDIM * LQ;
  f32x4 acc[4][4];
  #pragma unroll
  for (int mt = 0; mt < 4; ++mt)
    #pragma unroll
    for (int nt = 0; nt < 4; ++nt) acc[mt][nt] = (f32x4){0.f, 0.f, 0.f, 0.f};
  const int m0 = (w & 1) * 64, n0w = (w >> 1) * 64;
  const int row16 = l & 15, kq = l >> 4;
  for (int kk = 0; kk < 6; ++kk) {
    const int koff = kk * 64;
    #pragma unroll
    for (int s = 0; s < 4; ++s) {
      int slot = (s * 4 + w) * 64 + l;
      int rrow = slot >> 3, cc = slot & 7;
      int cg = cc ^ (rrow & 7);
      gl_lds16(Ab + (size_t)(i0 + rrow) * LQ + koff + cg * 8, &AB[0][slot * 8]);
      gl_lds16(Bb + (size_t)(n0 + rrow) * LQ + koff + cg * 8, &AB[1][slot * 8]);
    }
    asm volatile("s_waitcnt vmcnt(0)" ::: "memory");
    __syncthreads();
    #pragma unroll
    for (int kb = 0; kb < 2; ++kb) {
      bf16x8 af[4], bv[4];
      #pragma unroll
      for (int mt = 0; mt < 4; ++mt) {
        int r = m0 + mt * 16 + row16;
        int c = (kb * 4 + kq) ^ (r & 7);
        af[mt] = *(const bf16x8*)&AB[0][r * 64 + c * 8];
      }
      #pragma unroll
      for (int nt = 0; nt < 4; ++nt) {
        int r = n0w + nt * 16 + row16;
        int c = (kb * 4 + kq) ^ (r & 7);
        bv[nt] = *(const bf16x8*)&AB[1][r * 64 + c * 8];
      }
      #pragma unroll
      for (int mt = 0; mt < 4; ++mt)
        #pragma unroll
        for (int nt = 0; nt < 4; ++nt)
          acc[mt][nt] = __builtin_amdgcn_mfma_f32_16x16x32_bf16(af[mt], bv[nt], acc[mt][nt], 0, 0, 0);
    }
    __syncthreads();
  }
  // staged coalesced epilogue (reuse AB as 128x128 bf16 C-tile)
  us* C = &AB[0][0];
  #pragma unroll
  for (int mt = 0; mt < 4; ++mt)
    #pragma unroll
    for (int nt = 0; nt < 4; ++nt)
      #pragma unroll
      for (int v4 = 0; v4 < 4; ++v4)
        C[(m0 + mt * 16 + kq * 4 + v4) * 128 + n0w + nt * 16 + row16] = f2bf(acc[mt][nt][v4]);
  __syncthreads();
  #pragma unroll
  for (int it = 0; it < 8; ++it) {
    int slot = tid + 256 * it;      // 0..2047
    int mrow = slot >> 4, c = slot & 15;
    bf16x8 val = *(const bf16x8*)&C[mrow * 128 + c * 8];
    *(bf16x8*)&Ow[((size_t)h * LQ + i0 + mrow) * KDIM + n0 + c * 8] = val;
  }
}

// ---------------- K5: out[y,x,:] = (g[x,y] * o[x,y]) @ Wo + bo ----------------
__global__ __launch_bounds__(256) void k_final(
    const us* __restrict__ Gw, const us* __restrict__ Ow, const us* __restrict__ wt,
    const float* __restrict__ bo, float* __restrict__ out)
{
  __shared__ __attribute__((aligned(16))) us e_lds[64 * 128];
  const int tid = threadIdx.x, w = tid >> 6, l = tid & 63;
  const int y = blockIdx.x / 6, x0 = (blockIdx.x % 6) * 64;
  const int row16 = l & 15, kq = l >> 4;
  #pragma unroll
  for (int rr = 0; rr < 16; ++rr) {
    int m = w * 16 + rr;
    int x = x0 + m;
    const us* gr = Gw + ((size_t)x * LQ + y) * DPAIR;
    float gv0 = bf2f(gr[l]), gv1 = bf2f(gr[l + 64]);
    int h0 = l >> 5, d0 = l & 31;
    int l2 = l + 64, h1 = l2 >> 5, d1 = l2 & 31;
    float ov0 = bf2f(Ow[((size_t)h0 * LQ + x) * KDIM + y * 32 + d0]);
    float ov1 = bf2f(Ow[((size_t)h1 * LQ + x) * KDIM + y * 32 + d1]);
    int c0 = (l >> 3) ^ (m & 7);
    int c1 = ((l + 64) >> 3) ^ (m & 7);
    e_lds[m * 128 + c0 * 8 + (l & 7)] = f2bf(gv0 * ov0);
    e_lds[m * 128 + c1 * 8 + (l & 7)] = f2bf(gv1 * ov1);
  }
  __syncthreads();
  const us* W = wt + 4 * 16384;       // WoT
  f32x4 acc[4][2];
  #pragma unroll
  for (int mt = 0; mt < 4; ++mt) { acc[mt][0] = (f32x4){0.f,0.f,0.f,0.f}; acc[mt][1] = (f32x4){0.f,0.f,0.f,0.f}; }
  #pragma unroll
  for (int kb = 0; kb < 4; ++kb) {
    bf16x8 af[4], bv[2];
    #pragma unroll
    for (int mt = 0; mt < 4; ++mt) {
      int r = mt * 16 + row16;
      int c = (kb * 4 + kq) ^ (r & 7);
      af[mt] = *(const bf16x8*)&e_lds[r * 128 + c * 8];
    }
    #pragma unroll
    for (int nt = 0; nt < 2; ++nt)
      bv[nt] = *(const bf16x8*)&W[(w * 32 + nt * 16 + row16) * 128 + kb * 32 + kq * 8];
    #pragma unroll
    for (int mt = 0; mt < 4; ++mt)
      #pragma unroll
      for (int nt = 0; nt < 2; ++nt)
        acc[mt][nt] = __builtin_amdgcn_mfma_f32_16x16x32_bf16(af[mt], bv[nt], acc[mt][nt], 0, 0, 0);
  }
  #pragma unroll
  for (int nt = 0; nt < 2; ++nt) {
    int n = w * 32 + nt * 16 + row16;
    float bov = bo[n];
    #pragma unroll
    for (int mt = 0; mt < 4; ++mt)
      #pragma unroll
      for (int v4 = 0; v4 < 4; ++v4) {
        int m = mt * 16 + kq * 4 + v4;
        out[((size_t)y * LQ + x0 + m) * DPAIR + n] = acc[mt][nt][v4] + bov;
      }
  }
}

extern "C" void kernel_launch(void* const* d_in, const int* in_sizes, int n_in,
                              void* d_out, int out_size, void* d_ws, size_t ws_size,
                              hipStream_t stream)
{
  const float* pair = (const float*)d_in[0];
  const float* bias = (const float*)d_in[1];
  const float* lng  = (const float*)d_in[2];
  const float* lnb  = (const float*)d_in[3];
  const float* Wq   = (const float*)d_in[4];
  const float* Wk   = (const float*)d_in[5];
  const float* Wv   = (const float*)d_in[6];
  const float* Wb   = (const float*)d_in[7];
  const float* Wg   = (const float*)d_in[8];
  const float* bg   = (const float*)d_in[9];
  const float* Wo   = (const float*)d_in[10];
  const float* bo   = (const float*)d_in[11];

  char* ws = (char*)d_ws;
  us* wt     = (us*)(ws + WT_OFF);
  us* Qw     = (us*)(ws + Q_OFF);
  us* Kw     = (us*)(ws + K_OFF);
  us* Vw     = (us*)(ws + V_OFF);
  us* Gw     = (us*)(ws + G_OFF);
  us* attn   = (us*)(ws + ATT_OFF);
  float* logits = (float*)(ws + LOG_OFF);
  us* Ow = Qw;   // reuse

  hipMemsetAsync(logits, 0, (size_t)4 * 384 * 384 * 4, stream);
  k_pack<<<320, 256, 0, stream>>>(Wq, Wk, Wv, Wg, Wo, wt);
  k_ln_qkvg<<<2304, 256, 0, stream>>>(pair, lng, lnb, bg, wt, Qw, Kw, Vw, Gw);
  k_logits<<<288, 256, 0, stream>>>(Qw, Kw, logits);
  k_softmax<<<384, 256, 0, stream>>>(bias, Wb, logits, attn);
  k_ogemm<<<1152, 256, 0, stream>>>(attn, Vw, Ow);
  k_final<<<2304, 256, 0, stream>>>(Gw, Ow, wt, bo, (float*)d_out);
}

// Round 2
// 308.287 us; speedup vs baseline: 1.4061x; 1.4061x over previous
//
#include <hip/hip_runtime.h>
#include <math.h>

typedef unsigned short us;
typedef short bf16x8 __attribute__((ext_vector_type(8)));
typedef short bf16x4 __attribute__((ext_vector_type(4)));
typedef float f32x4 __attribute__((ext_vector_type(4)));

#define LQ 384
#define DPAIR 128
#define KDIM 12288  // L*32

// ws byte offsets
#define WT_OFF   0UL
#define P_OFF    262144UL
#define LOG_OFF  262144UL      // overlaps P (P dead before logits written)
#define ATT_OFF  2621440UL     // overlaps P (P dead before attn written)
#define Q_OFF    38010880UL
#define K_OFF    75759616UL
#define V_OFF    113508352UL
#define G_OFF    151257088UL
// Ow reuses Q's slot (Q dead after k_logits)

__device__ __forceinline__ us f2bf(float x){
  unsigned u = __builtin_bit_cast(unsigned, x);
  return (us)((u + 0x7FFFu + ((u >> 16) & 1u)) >> 16);
}
__device__ __forceinline__ float bf2f(us b){
  unsigned u = ((unsigned)b) << 16;
  return __builtin_bit_cast(float, u);
}
__device__ __forceinline__ void gl_lds16(const void* g, void* l){
  __builtin_amdgcn_global_load_lds((const __attribute__((address_space(1))) unsigned*)g,
                                   (__attribute__((address_space(3))) unsigned*)l, 16, 0, 0);
}
__device__ __forceinline__ float wsum(float x){
  #pragma unroll
  for (int o = 32; o; o >>= 1) x += __shfl_xor(x, o, 64);
  return x;
}
__device__ __forceinline__ float wmaxr(float x){
  #pragma unroll
  for (int o = 32; o; o >>= 1) x = fmaxf(x, __shfl_xor(x, o, 64));
  return x;
}

// ---------------- K0: pack transposed bf16 weights (scalings folded) ----------------
__global__ __launch_bounds__(256) void k_pack(
    const float* __restrict__ Wq, const float* __restrict__ Wk,
    const float* __restrict__ Wv, const float* __restrict__ Wg,
    const float* __restrict__ Wo, us* __restrict__ wt)
{
  int idx = blockIdx.x * 256 + threadIdx.x;       // < 5*16384
  int m = idx >> 14, rr = idx & 16383, n = rr >> 7, k = rr & 127;
  const float* W; float s;
  switch (m) {
    case 0: W = Wq; s = 0.17677669529663687f; break;   // 1/sqrt(32)
    case 1: W = Wk; s = 0.05103103630798287f; break;   // 1/sqrt(384)
    case 2: W = Wv; s = 1.f; break;
    case 3: W = Wg; s = 1.f; break;
    default: W = Wo; s = 1.f; break;
  }
  wt[idx] = f2bf(W[k * 128 + n] * s);                  // WT[n][k] = W[k][n]*s
}

// ---------------- K1a: LayerNorm transpose pass ----------------
// P[a*384+b][0..127] = bf16(LN(pair[b][a][:])).  1152 blocks x 4 waves,
// 32 rows per wave, 4-row ILP batches, no LDS -> full occupancy.
__global__ __launch_bounds__(256) void k_ln(
    const float* __restrict__ pair, const float* __restrict__ lng,
    const float* __restrict__ lnb, us* __restrict__ P)
{
  const int tid = threadIdx.x, w = tid >> 6, l = tid & 63;
  const int gw = blockIdx.x * 4 + w;            // 0..4607
  const int a = gw / 12, bb = (gw % 12) * 32;
  const float2 lg = ((const float2*)lng)[l];
  const float2 lb = ((const float2*)lnb)[l];
  for (int it = 0; it < 8; ++it) {
    float2 x[4];
    #pragma unroll
    for (int rr = 0; rr < 4; ++rr) {
      int b = bb + it * 4 + rr;
      x[rr] = ((const float2*)(pair + ((size_t)b * LQ + a) * DPAIR))[l];
    }
    #pragma unroll
    for (int rr = 0; rr < 4; ++rr) {
      float s = x[rr].x + x[rr].y;
      float q = x[rr].x * x[rr].x + x[rr].y * x[rr].y;
      s = wsum(s); q = wsum(q);
      float mu = s * (1.f / 128.f);
      float var = q * (1.f / 128.f) - mu * mu;
      float rstd = rsqrtf(var + 1e-5f);
      float y0 = (x[rr].x - mu) * rstd * lg.x + lb.x;
      float y1 = (x[rr].y - mu) * rstd * lg.y + lb.y;
      unsigned pk = (unsigned)f2bf(y0) | ((unsigned)f2bf(y1) << 16);
      int b = bb + it * 4 + rr;
      ((unsigned*)(P + ((size_t)(a * LQ + b)) * DPAIR))[l] = pk;
    }
  }
}

// ---------------- K1b: q/k/v/g projection GEMM ----------------
// C[128 rows (a,b0..b0+127)][128 cols] = P_tile @ WT_type^T, per-type epilogue.
// type: 0=Q, 1=K, 2=V(transposed store), 3=G(sigmoid, row-major)
__global__ __launch_bounds__(256) void k_qkvg(
    const us* __restrict__ P, const us* __restrict__ wt,
    const float* __restrict__ bg,
    us* __restrict__ Qw, us* __restrict__ Kw, us* __restrict__ Vw, us* __restrict__ Gw)
{
  __shared__ __attribute__((aligned(16))) us lds[17408];   // 34816 B
  const int tid = threadIdx.x, w = tid >> 6, l = tid & 63;
  const int mtile = blockIdx.x >> 2, type = blockIdx.x & 3;
  const int a = mtile / 3, b0 = (mtile % 3) * 128;
  const size_t Prow0 = (size_t)a * LQ + b0;
  const us* W = wt + type * 16384;
  us* Abuf = lds;           // [128][64] swizzled
  us* Bbuf = lds + 8192;
  f32x4 acc[4][4];
  #pragma unroll
  for (int mt = 0; mt < 4; ++mt)
    #pragma unroll
    for (int nt = 0; nt < 4; ++nt) acc[mt][nt] = (f32x4){0.f, 0.f, 0.f, 0.f};
  const int m0 = (w & 1) * 64, n0 = (w >> 1) * 64;
  const int row16 = l & 15, kq = l >> 4;
  #pragma unroll
  for (int ks = 0; ks < 2; ++ks) {
    const int koff = ks * 64;
    #pragma unroll
    for (int s = 0; s < 4; ++s) {
      int slot = (s * 4 + w) * 64 + l;
      int rrow = slot >> 3, cc = slot & 7;
      int cg = cc ^ (rrow & 7);
      gl_lds16(P + (Prow0 + rrow) * DPAIR + koff + cg * 8, &Abuf[slot * 8]);
      gl_lds16(W + rrow * DPAIR + koff + cg * 8, &Bbuf[slot * 8]);
    }
    asm volatile("s_waitcnt vmcnt(0)" ::: "memory");
    __syncthreads();
    #pragma unroll
    for (int kb = 0; kb < 2; ++kb) {
      bf16x8 af[4], bv[4];
      #pragma unroll
      for (int mt = 0; mt < 4; ++mt) {
        int r = m0 + mt * 16 + row16;
        int c = (kb * 4 + kq) ^ (r & 7);
        af[mt] = *(const bf16x8*)&Abuf[r * 64 + c * 8];
      }
      #pragma unroll
      for (int nt = 0; nt < 4; ++nt) {
        int r = n0 + nt * 16 + row16;
        int c = (kb * 4 + kq) ^ (r & 7);
        bv[nt] = *(const bf16x8*)&Bbuf[r * 64 + c * 8];
      }
      #pragma unroll
      for (int mt = 0; mt < 4; ++mt)
        #pragma unroll
        for (int nt = 0; nt < 4; ++nt)
          acc[mt][nt] = __builtin_amdgcn_mfma_f32_16x16x32_bf16(af[mt], bv[nt], acc[mt][nt], 0, 0, 0);
    }
    __syncthreads();
  }

  if (type == 2) {
    // V: stage transposed T[col(d) * 132 + row(j)], u32-packed writes
    us* T = lds;
    #pragma unroll
    for (int nt = 0; nt < 4; ++nt) {
      int col = n0 + nt * 16 + row16;
      #pragma unroll
      for (int mt = 0; mt < 4; ++mt) {
        int rowb = m0 + mt * 16 + kq * 4;
        f32x4 vv = acc[mt][nt];
        *(unsigned*)&T[col * 132 + rowb]     = (unsigned)f2bf(vv[0]) | ((unsigned)f2bf(vv[1]) << 16);
        *(unsigned*)&T[col * 132 + rowb + 2] = (unsigned)f2bf(vv[2]) | ((unsigned)f2bf(vv[3]) << 16);
      }
    }
    __syncthreads();
    #pragma unroll
    for (int it = 0; it < 8; ++it) {
      int slot = tid + 256 * it;       // 0..2047
      int d = slot >> 4, jc = slot & 15;
      bf16x4 lo = *(const bf16x4*)&T[d * 132 + jc * 8];
      bf16x4 hi = *(const bf16x4*)&T[d * 132 + jc * 8 + 4];
      bf16x8 val = __builtin_shufflevector(lo, hi, 0, 1, 2, 3, 4, 5, 6, 7);
      int h = d >> 5, dd = d & 31;
      *(bf16x8*)&Vw[((size_t)h * KDIM + a * 32 + dd) * LQ + b0 + jc * 8] = val;
    }
  } else {
    // Q/K/G: stage row-major Cs[row * 136 + col]
    us* Cs = lds;
    #pragma unroll
    for (int nt = 0; nt < 4; ++nt) {
      int col = n0 + nt * 16 + row16;
      float bgv = (type == 3) ? bg[col] : 0.f;
      #pragma unroll
      for (int mt = 0; mt < 4; ++mt) {
        f32x4 vv = acc[mt][nt];
        #pragma unroll
        for (int v4 = 0; v4 < 4; ++v4) {
          float x = vv[v4];
          if (type == 3) {
            float e = __expf(-(x + bgv));
            x = 1.f / (1.f + e);
          }
          Cs[(m0 + mt * 16 + kq * 4 + v4) * 136 + col] = f2bf(x);
        }
      }
    }
    __syncthreads();
    #pragma unroll
    for (int it = 0; it < 8; ++it) {
      int slot = tid + 256 * it;       // 0..2047
      int row = slot >> 4, chunk = slot & 15;
      bf16x8 val = *(const bf16x8*)&Cs[row * 136 + chunk * 8];
      if (type == 3) {
        *(bf16x8*)&Gw[((size_t)(a * LQ + b0 + row)) * DPAIR + chunk * 8] = val;
      } else {
        int h = chunk >> 2, c8 = chunk & 3;
        us* dst = (type == 0) ? Qw : Kw;
        *(bf16x8*)&dst[((size_t)(h * LQ + b0 + row)) * KDIM + a * 32 + c8 * 8] = val;
      }
    }
  }
}

// ---------------- K2: logits GEMM (K-split 8, atomicAdd fp32) ----------------
__global__ __launch_bounds__(256) void k_logits(
    const us* __restrict__ Qw, const us* __restrict__ Kw, float* __restrict__ logits)
{
  __shared__ __attribute__((aligned(16))) us AB[2][128 * 64];
  const int tid = threadIdx.x, w = tid >> 6, l = tid & 63;
  const int bx = blockIdx.x;
  const int h = bx / 72, r2 = bx % 72, ks = r2 / 9, t = r2 % 9;
  const int i0 = (t / 3) * 128, j0 = (t % 3) * 128;
  const us* Ab = Qw + (size_t)h * LQ * KDIM;
  const us* Bb = Kw + (size_t)h * LQ * KDIM;
  f32x4 acc[4][4];
  #pragma unroll
  for (int mt = 0; mt < 4; ++mt)
    #pragma unroll
    for (int nt = 0; nt < 4; ++nt) acc[mt][nt] = (f32x4){0.f, 0.f, 0.f, 0.f};
  const int m0 = (w & 1) * 64, n0 = (w >> 1) * 64;
  const int row16 = l & 15, kq = l >> 4;
  for (int kk = 0; kk < 24; ++kk) {
    const int koff = ks * 1536 + kk * 64;
    #pragma unroll
    for (int s = 0; s < 4; ++s) {
      int slot = (s * 4 + w) * 64 + l;
      int rrow = slot >> 3, cc = slot & 7;
      int cg = cc ^ (rrow & 7);
      gl_lds16(Ab + (size_t)(i0 + rrow) * KDIM + koff + cg * 8, &AB[0][slot * 8]);
      gl_lds16(Bb + (size_t)(j0 + rrow) * KDIM + koff + cg * 8, &AB[1][slot * 8]);
    }
    asm volatile("s_waitcnt vmcnt(0)" ::: "memory");
    __syncthreads();
    #pragma unroll
    for (int kb = 0; kb < 2; ++kb) {
      bf16x8 af[4], bv[4];
      #pragma unroll
      for (int mt = 0; mt < 4; ++mt) {
        int r = m0 + mt * 16 + row16;
        int c = (kb * 4 + kq) ^ (r & 7);
        af[mt] = *(const bf16x8*)&AB[0][r * 64 + c * 8];
      }
      #pragma unroll
      for (int nt = 0; nt < 4; ++nt) {
        int r = n0 + nt * 16 + row16;
        int c = (kb * 4 + kq) ^ (r & 7);
        bv[nt] = *(const bf16x8*)&AB[1][r * 64 + c * 8];
      }
      #pragma unroll
      for (int mt = 0; mt < 4; ++mt)
        #pragma unroll
        for (int nt = 0; nt < 4; ++nt)
          acc[mt][nt] = __builtin_amdgcn_mfma_f32_16x16x32_bf16(af[mt], bv[nt], acc[mt][nt], 0, 0, 0);
    }
    __syncthreads();
  }
  #pragma unroll
  for (int mt = 0; mt < 4; ++mt)
    #pragma unroll
    for (int nt = 0; nt < 4; ++nt)
      #pragma unroll
      for (int v4 = 0; v4 < 4; ++v4) {
        int i = i0 + m0 + mt * 16 + kq * 4 + v4;
        int j = j0 + n0 + nt * 16 + row16;
        atomicAdd(&logits[((size_t)h * LQ + i) * LQ + j], acc[mt][nt][v4]);
      }
}

// ---------------- K3: bias@Wb + softmax over j ----------------
__global__ __launch_bounds__(256) void k_softmax(
    const float* __restrict__ bias, const float* __restrict__ Wb,
    const float* __restrict__ logits, us* __restrict__ attn)
{
  __shared__ float bp[4][LQ];
  const int tid = threadIdx.x, w = tid >> 6, l = tid & 63;
  const int i = blockIdx.x;
  const float4* Wb4 = (const float4*)Wb;          // Wb row = float4
  const float4 w0 = Wb4[l], w1 = Wb4[l + 64];
  for (int jt = 0; jt < 96; ++jt) {
    int j = jt * 4 + w;
    const float* br = bias + ((size_t)i * LQ + j) * DPAIR;
    float bv0 = br[l], bv1 = br[l + 64];
    float p0 = bv0 * w0.x + bv1 * w1.x;
    float p1 = bv0 * w0.y + bv1 * w1.y;
    float p2 = bv0 * w0.z + bv1 * w1.z;
    float p3 = bv0 * w0.w + bv1 * w1.w;
    #pragma unroll
    for (int o = 32; o; o >>= 1) {
      p0 += __shfl_xor(p0, o, 64);
      p1 += __shfl_xor(p1, o, 64);
      p2 += __shfl_xor(p2, o, 64);
      p3 += __shfl_xor(p3, o, 64);
    }
    if (l == 0) { bp[0][j] = p0; bp[1][j] = p1; bp[2][j] = p2; bp[3][j] = p3; }
  }
  __syncthreads();
  const int h = w;
  const float* lrow = logits + ((size_t)h * LQ + i) * LQ;
  float x[6];
  #pragma unroll
  for (int s = 0; s < 6; ++s) x[s] = lrow[l + 64 * s] + bp[h][l + 64 * s];
  float mx = x[0];
  #pragma unroll
  for (int s = 1; s < 6; ++s) mx = fmaxf(mx, x[s]);
  mx = wmaxr(mx);
  float e[6], sum = 0.f;
  #pragma unroll
  for (int s = 0; s < 6; ++s) { e[s] = expf(x[s] - mx); sum += e[s]; }
  sum = wsum(sum);
  float rinv = 1.f / sum;
  #pragma unroll
  for (int s = 0; s < 6; ++s)
    attn[((size_t)h * LQ + i) * LQ + l + 64 * s] = f2bf(e[s] * rinv);
}

// ---------------- K4: o = attn @ V^T per head ----------------
__global__ __launch_bounds__(256) void k_ogemm(
    const us* __restrict__ attn, const us* __restrict__ Vw, us* __restrict__ Ow)
{
  __shared__ __attribute__((aligned(16))) us AB[2][128 * 64];
  const int tid = threadIdx.x, w = tid >> 6, l = tid & 63;
  const int bx = blockIdx.x;
  const int h = bx / 288, r2 = bx % 288;
  const int i0 = (r2 / 96) * 128, n0 = (r2 % 96) * 128;
  const us* Ab = attn + (size_t)h * LQ * LQ;
  const us* Bb = Vw + (size_t)h * KDIM * LQ;
  f32x4 acc[4][4];
  #pragma unroll
  for (int mt = 0; mt < 4; ++mt)
    #pragma unroll
    for (int nt = 0; nt < 4; ++nt) acc[mt][nt] = (f32x4){0.f, 0.f, 0.f, 0.f};
  const int m0 = (w & 1) * 64, n0w = (w >> 1) * 64;
  const int row16 = l & 15, kq = l >> 4;
  for (int kk = 0; kk < 6; ++kk) {
    const int koff = kk * 64;
    #pragma unroll
    for (int s = 0; s < 4; ++s) {
      int slot = (s * 4 + w) * 64 + l;
      int rrow = slot >> 3, cc = slot & 7;
      int cg = cc ^ (rrow & 7);
      gl_lds16(Ab + (size_t)(i0 + rrow) * LQ + koff + cg * 8, &AB[0][slot * 8]);
      gl_lds16(Bb + (size_t)(n0 + rrow) * LQ + koff + cg * 8, &AB[1][slot * 8]);
    }
    asm volatile("s_waitcnt vmcnt(0)" ::: "memory");
    __syncthreads();
    #pragma unroll
    for (int kb = 0; kb < 2; ++kb) {
      bf16x8 af[4], bv[4];
      #pragma unroll
      for (int mt = 0; mt < 4; ++mt) {
        int r = m0 + mt * 16 + row16;
        int c = (kb * 4 + kq) ^ (r & 7);
        af[mt] = *(const bf16x8*)&AB[0][r * 64 + c * 8];
      }
      #pragma unroll
      for (int nt = 0; nt < 4; ++nt) {
        int r = n0w + nt * 16 + row16;
        int c = (kb * 4 + kq) ^ (r & 7);
        bv[nt] = *(const bf16x8*)&AB[1][r * 64 + c * 8];
      }
      #pragma unroll
      for (int mt = 0; mt < 4; ++mt)
        #pragma unroll
        for (int nt = 0; nt < 4; ++nt)
          acc[mt][nt] = __builtin_amdgcn_mfma_f32_16x16x32_bf16(af[mt], bv[nt], acc[mt][nt], 0, 0, 0);
    }
    __syncthreads();
  }
  // staged coalesced epilogue (reuse AB as 128x128 bf16 C-tile)
  us* C = &AB[0][0];
  #pragma unroll
  for (int mt = 0; mt < 4; ++mt)
    #pragma unroll
    for (int nt = 0; nt < 4; ++nt)
      #pragma unroll
      for (int v4 = 0; v4 < 4; ++v4)
        C[(m0 + mt * 16 + kq * 4 + v4) * 128 + n0w + nt * 16 + row16] = f2bf(acc[mt][nt][v4]);
  __syncthreads();
  #pragma unroll
  for (int it = 0; it < 8; ++it) {
    int slot = tid + 256 * it;      // 0..2047
    int mrow = slot >> 4, c = slot & 15;
    bf16x8 val = *(const bf16x8*)&C[mrow * 128 + c * 8];
    *(bf16x8*)&Ow[((size_t)h * LQ + i0 + mrow) * KDIM + n0 + c * 8] = val;
  }
}

// ---------------- K5: out[y,x,:] = (g[x,y] * o[x,y]) @ Wo + bo ----------------
__global__ __launch_bounds__(256) void k_final(
    const us* __restrict__ Gw, const us* __restrict__ Ow, const us* __restrict__ wt,
    const float* __restrict__ bo, float* __restrict__ out)
{
  __shared__ __attribute__((aligned(16))) us e_lds[64 * 128];
  const int tid = threadIdx.x, w = tid >> 6, l = tid & 63;
  const int y = blockIdx.x / 6, x0 = (blockIdx.x % 6) * 64;
  const int row16 = l & 15, kq = l >> 4;
  #pragma unroll
  for (int rr = 0; rr < 16; ++rr) {
    int m = w * 16 + rr;
    int x = x0 + m;
    const us* gr = Gw + ((size_t)x * LQ + y) * DPAIR;
    float gv0 = bf2f(gr[l]), gv1 = bf2f(gr[l + 64]);
    int h0 = l >> 5, d0 = l & 31;
    int l2 = l + 64, h1 = l2 >> 5, d1 = l2 & 31;
    float ov0 = bf2f(Ow[((size_t)h0 * LQ + x) * KDIM + y * 32 + d0]);
    float ov1 = bf2f(Ow[((size_t)h1 * LQ + x) * KDIM + y * 32 + d1]);
    int c0 = (l >> 3) ^ (m & 7);
    int c1 = ((l + 64) >> 3) ^ (m & 7);
    e_lds[m * 128 + c0 * 8 + (l & 7)] = f2bf(gv0 * ov0);
    e_lds[m * 128 + c1 * 8 + (l & 7)] = f2bf(gv1 * ov1);
  }
  __syncthreads();
  const us* W = wt + 4 * 16384;       // WoT
  f32x4 acc[4][2];
  #pragma unroll
  for (int mt = 0; mt < 4; ++mt) { acc[mt][0] = (f32x4){0.f,0.f,0.f,0.f}; acc[mt][1] = (f32x4){0.f,0.f,0.f,0.f}; }
  #pragma unroll
  for (int kb = 0; kb < 4; ++kb) {
    bf16x8 af[4], bv[2];
    #pragma unroll
    for (int mt = 0; mt < 4; ++mt) {
      int r = mt * 16 + row16;
      int c = (kb * 4 + kq) ^ (r & 7);
      af[mt] = *(const bf16x8*)&e_lds[r * 128 + c * 8];
    }
    #pragma unroll
    for (int nt = 0; nt < 2; ++nt)
      bv[nt] = *(const bf16x8*)&W[(w * 32 + nt * 16 + row16) * 128 + kb * 32 + kq * 8];
    #pragma unroll
    for (int mt = 0; mt < 4; ++mt)
      #pragma unroll
      for (int nt = 0; nt < 2; ++nt)
        acc[mt][nt] = __builtin_amdgcn_mfma_f32_16x16x32_bf16(af[mt], bv[nt], acc[mt][nt], 0, 0, 0);
  }
  #pragma unroll
  for (int nt = 0; nt < 2; ++nt) {
    int n = w * 32 + nt * 16 + row16;
    float bov = bo[n];
    #pragma unroll
    for (int mt = 0; mt < 4; ++mt)
      #pragma unroll
      for (int v4 = 0; v4 < 4; ++v4) {
        int m = mt * 16 + kq * 4 + v4;
        out[((size_t)y * LQ + x0 + m) * DPAIR + n] = acc[mt][nt][v4] + bov;
      }
  }
}

extern "C" void kernel_launch(void* const* d_in, const int* in_sizes, int n_in,
                              void* d_out, int out_size, void* d_ws, size_t ws_size,
                              hipStream_t stream)
{
  const float* pair = (const float*)d_in[0];
  const float* bias = (const float*)d_in[1];
  const float* lng  = (const float*)d_in[2];
  const float* lnb  = (const float*)d_in[3];
  const float* Wq   = (const float*)d_in[4];
  const float* Wk   = (const float*)d_in[5];
  const float* Wv   = (const float*)d_in[6];
  const float* Wb   = (const float*)d_in[7];
  const float* Wg   = (const float*)d_in[8];
  const float* bg   = (const float*)d_in[9];
  const float* Wo   = (const float*)d_in[10];
  const float* bo   = (const float*)d_in[11];

  char* ws = (char*)d_ws;
  us* wt     = (us*)(ws + WT_OFF);
  us* P      = (us*)(ws + P_OFF);
  us* Qw     = (us*)(ws + Q_OFF);
  us* Kw     = (us*)(ws + K_OFF);
  us* Vw     = (us*)(ws + V_OFF);
  us* Gw     = (us*)(ws + G_OFF);
  us* attn   = (us*)(ws + ATT_OFF);
  float* logits = (float*)(ws + LOG_OFF);
  us* Ow = Qw;   // reuse (Q dead after k_logits)

  k_pack<<<320, 256, 0, stream>>>(Wq, Wk, Wv, Wg, Wo, wt);
  k_ln<<<1152, 256, 0, stream>>>(pair, lng, lnb, P);
  k_qkvg<<<4608, 256, 0, stream>>>(P, wt, bg, Qw, Kw, Vw, Gw);
  // logits/attn overlap P's region: P must be dead before this memset
  hipMemsetAsync(logits, 0, (size_t)4 * LQ * LQ * 4, stream);
  k_logits<<<288, 256, 0, stream>>>(Qw, Kw, logits);
  k_softmax<<<384, 256, 0, stream>>>(bias, Wb, logits, attn);
  k_ogemm<<<1152, 256, 0, stream>>>(attn, Vw, Ow);
  k_final<<<2304, 256, 0, stream>>>(Gw, Ow, wt, bo, (float*)d_out);
}

// Round 3
// 306.439 us; speedup vs baseline: 1.4146x; 1.0060x over previous
//
#include <hip/hip_runtime.h>
#include <math.h>

typedef unsigned short us;
typedef short bf16x8 __attribute__((ext_vector_type(8)));
typedef short bf16x4 __attribute__((ext_vector_type(4)));
typedef float f32x4 __attribute__((ext_vector_type(4)));

#define LQ 384
#define DPAIR 128
#define KDIM 12288  // L*32

// ws byte offsets
#define WT_OFF   0UL
#define LOG_OFF  262144UL
#define ATT_OFF  2621440UL
#define Q_OFF    38010880UL
#define K_OFF    75759616UL
#define V_OFF    113508352UL
#define G_OFF    151257088UL

__device__ __forceinline__ us f2bf(float x){
  unsigned u = __builtin_bit_cast(unsigned, x);
  return (us)((u + 0x7FFFu + ((u >> 16) & 1u)) >> 16);
}
__device__ __forceinline__ float bf2f(us b){
  unsigned u = ((unsigned)b) << 16;
  return __builtin_bit_cast(float, u);
}
__device__ __forceinline__ void gl_lds16(const void* g, void* l){
  __builtin_amdgcn_global_load_lds((const __attribute__((address_space(1))) unsigned*)g,
                                   (__attribute__((address_space(3))) unsigned*)l, 16, 0, 0);
}
__device__ __forceinline__ float wsum(float x){
  #pragma unroll
  for (int o = 32; o; o >>= 1) x += __shfl_xor(x, o, 64);
  return x;
}
__device__ __forceinline__ float wmaxr(float x){
  #pragma unroll
  for (int o = 32; o; o >>= 1) x = fmaxf(x, __shfl_xor(x, o, 64));
  return x;
}

// ---------------- K0: pack transposed bf16 weights (scalings folded) ----------------
__global__ __launch_bounds__(256) void k_pack(
    const float* __restrict__ Wq, const float* __restrict__ Wk,
    const float* __restrict__ Wv, const float* __restrict__ Wg,
    const float* __restrict__ Wo, us* __restrict__ wt)
{
  int idx = blockIdx.x * 256 + threadIdx.x;       // < 5*16384
  int m = idx >> 14, rr = idx & 16383, n = rr >> 7, k = rr & 127;
  const float* W; float s;
  switch (m) {
    case 0: W = Wq; s = 0.17677669529663687f; break;   // 1/sqrt(32)
    case 1: W = Wk; s = 0.05103103630798287f; break;   // 1/sqrt(384)
    case 2: W = Wv; s = 1.f; break;
    case 3: W = Wg; s = 1.f; break;
    default: W = Wo; s = 1.f; break;
  }
  wt[idx] = f2bf(W[k * 128 + n] * s);                  // WT[n][k] = W[k][n]*s
}

// ---------------- K1: fused LayerNorm + q/k/v/g projections ----------------
// Block (a, b0..b0+127): LN rows in-register -> swizzled A_lds[128][128],
// then 4 types of C = A @ WT_type^T with W frags straight from global (L2-hot).
__global__ __launch_bounds__(256) void k_lnqkvg(
    const float* __restrict__ pair, const float* __restrict__ lng,
    const float* __restrict__ lnb, const float* __restrict__ bg,
    const us* __restrict__ wt,
    us* __restrict__ Qw, us* __restrict__ Kw, us* __restrict__ Vw, us* __restrict__ Gw)
{
  __shared__ __attribute__((aligned(16))) us A[128 * 128];     // 32 KB
  __shared__ __attribute__((aligned(16))) us Cst[17408];       // 34.8 KB stage
  const int tid = threadIdx.x, w = tid >> 6, l = tid & 63;
  const int a = blockIdx.x / 3, b0 = (blockIdx.x % 3) * 128;
  // ---- LN phase: wave w handles rows w*32..w*32+31, 4-row ILP ----
  const float2 lg = ((const float2*)lng)[l];
  const float2 lb = ((const float2*)lnb)[l];
  for (int it = 0; it < 8; ++it) {
    float2 x[4];
    #pragma unroll
    for (int rr = 0; rr < 4; ++rr) {
      int m = w * 32 + it * 4 + rr;
      x[rr] = ((const float2*)(pair + ((size_t)(b0 + m) * LQ + a) * DPAIR))[l];
    }
    #pragma unroll
    for (int rr = 0; rr < 4; ++rr) {
      int m = w * 32 + it * 4 + rr;
      float s = wsum(x[rr].x + x[rr].y);
      float q = wsum(x[rr].x * x[rr].x + x[rr].y * x[rr].y);
      float mu = s * (1.f / 128.f);
      float var = q * (1.f / 128.f) - mu * mu;
      float rstd = rsqrtf(var + 1e-5f);
      float y0 = (x[rr].x - mu) * rstd * lg.x + lb.x;
      float y1 = (x[rr].y - mu) * rstd * lg.y + lb.y;
      unsigned pk = (unsigned)f2bf(y0) | ((unsigned)f2bf(y1) << 16);
      // lane l holds cols 2l,2l+1 -> chunk=l>>2, swizzle ^(m&7), word (l&3)
      ((unsigned*)A)[m * 64 + (((l >> 2) ^ (m & 7)) << 2) + (l & 3)] = pk;
    }
  }
  __syncthreads();

  const int m0 = (w & 1) * 64, n0 = (w >> 1) * 64;
  const int row16 = l & 15, kq = l >> 4;
  for (int type = 0; type < 4; ++type) {
    const us* W = wt + type * 16384;
    // B fragments straight from global (L2-resident)
    bf16x8 bv[4][4];
    #pragma unroll
    for (int nt = 0; nt < 4; ++nt)
      #pragma unroll
      for (int kb = 0; kb < 4; ++kb)
        bv[nt][kb] = *(const bf16x8*)&W[(n0 + nt * 16 + row16) * 128 + kb * 32 + kq * 8];
    f32x4 acc[4][4];
    #pragma unroll
    for (int mt = 0; mt < 4; ++mt)
      #pragma unroll
      for (int nt = 0; nt < 4; ++nt) acc[mt][nt] = (f32x4){0.f, 0.f, 0.f, 0.f};
    #pragma unroll
    for (int kb = 0; kb < 4; ++kb) {
      bf16x8 af[4];
      #pragma unroll
      for (int mt = 0; mt < 4; ++mt) {
        int r = m0 + mt * 16 + row16;
        int c = (kb * 4 + kq) ^ (r & 7);
        af[mt] = *(const bf16x8*)&A[r * 128 + c * 8];
      }
      #pragma unroll
      for (int mt = 0; mt < 4; ++mt)
        #pragma unroll
        for (int nt = 0; nt < 4; ++nt)
          acc[mt][nt] = __builtin_amdgcn_mfma_f32_16x16x32_bf16(af[mt], bv[nt][kb], acc[mt][nt], 0, 0, 0);
    }
    // ---- epilogue per type ----
    if (type == 2) {
      // V: transposed stage T[d * 132 + j]
      us* T = Cst;
      #pragma unroll
      for (int nt = 0; nt < 4; ++nt) {
        int col = n0 + nt * 16 + row16;
        #pragma unroll
        for (int mt = 0; mt < 4; ++mt) {
          int rowb = m0 + mt * 16 + kq * 4;
          f32x4 vv = acc[mt][nt];
          *(unsigned*)&T[col * 132 + rowb]     = (unsigned)f2bf(vv[0]) | ((unsigned)f2bf(vv[1]) << 16);
          *(unsigned*)&T[col * 132 + rowb + 2] = (unsigned)f2bf(vv[2]) | ((unsigned)f2bf(vv[3]) << 16);
        }
      }
      __syncthreads();
      #pragma unroll
      for (int it = 0; it < 8; ++it) {
        int slot = tid + 256 * it;       // 0..2047
        int d = slot >> 4, jc = slot & 15;
        bf16x4 lo = *(const bf16x4*)&T[d * 132 + jc * 8];
        bf16x4 hi = *(const bf16x4*)&T[d * 132 + jc * 8 + 4];
        bf16x8 val = __builtin_shufflevector(lo, hi, 0, 1, 2, 3, 4, 5, 6, 7);
        int h = d >> 5, dd = d & 31;
        *(bf16x8*)&Vw[((size_t)h * KDIM + a * 32 + dd) * LQ + b0 + jc * 8] = val;
      }
      __syncthreads();
    } else {
      us* Cs = Cst;   // [row][stride 136]
      #pragma unroll
      for (int nt = 0; nt < 4; ++nt) {
        int col = n0 + nt * 16 + row16;
        float bgv = (type == 3) ? bg[col] : 0.f;
        #pragma unroll
        for (int mt = 0; mt < 4; ++mt) {
          f32x4 vv = acc[mt][nt];
          #pragma unroll
          for (int v4 = 0; v4 < 4; ++v4) {
            float x = vv[v4];
            if (type == 3) {
              float e = __expf(-(x + bgv));
              x = 1.f / (1.f + e);
            }
            Cs[(m0 + mt * 16 + kq * 4 + v4) * 136 + col] = f2bf(x);
          }
        }
      }
      __syncthreads();
      #pragma unroll
      for (int it = 0; it < 8; ++it) {
        int slot = tid + 256 * it;       // 0..2047
        int row = slot >> 4, chunk = slot & 15;
        bf16x8 val = *(const bf16x8*)&Cs[row * 136 + chunk * 8];
        if (type == 3) {
          *(bf16x8*)&Gw[((size_t)(a * LQ + b0 + row)) * DPAIR + chunk * 8] = val;
        } else {
          int h = chunk >> 2, c8 = chunk & 3;
          us* dst = (type == 0) ? Qw : Kw;
          *(bf16x8*)&dst[((size_t)(h * LQ + b0 + row)) * KDIM + a * 32 + c8 * 8] = val;
        }
      }
      __syncthreads();
    }
  }
}

// ---------------- K2: logits GEMM (K-split 8, atomicAdd fp32) ----------------
// XCD sibling grouping: the 3 j0-blocks sharing a Q-panel get equal bx%8.
__global__ __launch_bounds__(256) void k_logits(
    const us* __restrict__ Qw, const us* __restrict__ Kw, float* __restrict__ logits)
{
  __shared__ __attribute__((aligned(16))) us AB[2][128 * 64];
  const int tid = threadIdx.x, w = tid >> 6, l = tid & 63;
  const int bx = blockIdx.x;
  const int xg = bx & 7, yg = bx >> 3;           // 288 blocks: xg XCD, yg 0..35
  const int set = xg * 12 + yg / 3, j0 = (yg % 3) * 128;
  const int h = set / 24, rset = set % 24, i0 = (rset / 8) * 128, ks = rset % 8;
  const us* Ab = Qw + (size_t)h * LQ * KDIM;
  const us* Bb = Kw + (size_t)h * LQ * KDIM;
  f32x4 acc[4][4];
  #pragma unroll
  for (int mt = 0; mt < 4; ++mt)
    #pragma unroll
    for (int nt = 0; nt < 4; ++nt) acc[mt][nt] = (f32x4){0.f, 0.f, 0.f, 0.f};
  const int m0 = (w & 1) * 64, n0 = (w >> 1) * 64;
  const int row16 = l & 15, kq = l >> 4;
  for (int kk = 0; kk < 24; ++kk) {
    const int koff = ks * 1536 + kk * 64;
    #pragma unroll
    for (int s = 0; s < 4; ++s) {
      int slot = (s * 4 + w) * 64 + l;
      int rrow = slot >> 3, cc = slot & 7;
      int cg = cc ^ (rrow & 7);
      gl_lds16(Ab + (size_t)(i0 + rrow) * KDIM + koff + cg * 8, &AB[0][slot * 8]);
      gl_lds16(Bb + (size_t)(j0 + rrow) * KDIM + koff + cg * 8, &AB[1][slot * 8]);
    }
    asm volatile("s_waitcnt vmcnt(0)" ::: "memory");
    __syncthreads();
    #pragma unroll
    for (int kb = 0; kb < 2; ++kb) {
      bf16x8 af[4], bv[4];
      #pragma unroll
      for (int mt = 0; mt < 4; ++mt) {
        int r = m0 + mt * 16 + row16;
        int c = (kb * 4 + kq) ^ (r & 7);
        af[mt] = *(const bf16x8*)&AB[0][r * 64 + c * 8];
      }
      #pragma unroll
      for (int nt = 0; nt < 4; ++nt) {
        int r = n0 + nt * 16 + row16;
        int c = (kb * 4 + kq) ^ (r & 7);
        bv[nt] = *(const bf16x8*)&AB[1][r * 64 + c * 8];
      }
      #pragma unroll
      for (int mt = 0; mt < 4; ++mt)
        #pragma unroll
        for (int nt = 0; nt < 4; ++nt)
          acc[mt][nt] = __builtin_amdgcn_mfma_f32_16x16x32_bf16(af[mt], bv[nt], acc[mt][nt], 0, 0, 0);
    }
    __syncthreads();
  }
  #pragma unroll
  for (int mt = 0; mt < 4; ++mt)
    #pragma unroll
    for (int nt = 0; nt < 4; ++nt)
      #pragma unroll
      for (int v4 = 0; v4 < 4; ++v4) {
        int i = i0 + m0 + mt * 16 + kq * 4 + v4;
        int j = j0 + n0 + nt * 16 + row16;
        atomicAdd(&logits[((size_t)h * LQ + i) * LQ + j], acc[mt][nt][v4]);
      }
}

// ---------------- K3: bias@Wb + softmax over j ----------------
__global__ __launch_bounds__(256) void k_softmax(
    const float* __restrict__ bias, const float* __restrict__ Wb,
    const float* __restrict__ logits, us* __restrict__ attn)
{
  __shared__ float bp[4][LQ];
  const int tid = threadIdx.x, w = tid >> 6, l = tid & 63;
  const int i = blockIdx.x;
  const float4* Wb4 = (const float4*)Wb;          // Wb row = float4
  const float4 w0 = Wb4[l], w1 = Wb4[l + 64];
  for (int jt = 0; jt < 96; ++jt) {
    int j = jt * 4 + w;
    const float* br = bias + ((size_t)i * LQ + j) * DPAIR;
    float bv0 = br[l], bv1 = br[l + 64];
    float p0 = bv0 * w0.x + bv1 * w1.x;
    float p1 = bv0 * w0.y + bv1 * w1.y;
    float p2 = bv0 * w0.z + bv1 * w1.z;
    float p3 = bv0 * w0.w + bv1 * w1.w;
    #pragma unroll
    for (int o = 32; o; o >>= 1) {
      p0 += __shfl_xor(p0, o, 64);
      p1 += __shfl_xor(p1, o, 64);
      p2 += __shfl_xor(p2, o, 64);
      p3 += __shfl_xor(p3, o, 64);
    }
    if (l == 0) { bp[0][j] = p0; bp[1][j] = p1; bp[2][j] = p2; bp[3][j] = p3; }
  }
  __syncthreads();
  const int h = w;
  const float* lrow = logits + ((size_t)h * LQ + i) * LQ;
  float x[6];
  #pragma unroll
  for (int s = 0; s < 6; ++s) x[s] = lrow[l + 64 * s] + bp[h][l + 64 * s];
  float mx = x[0];
  #pragma unroll
  for (int s = 1; s < 6; ++s) mx = fmaxf(mx, x[s]);
  mx = wmaxr(mx);
  float e[6], sum = 0.f;
  #pragma unroll
  for (int s = 0; s < 6; ++s) { e[s] = expf(x[s] - mx); sum += e[s]; }
  sum = wsum(sum);
  float rinv = 1.f / sum;
  #pragma unroll
  for (int s = 0; s < 6; ++s)
    attn[((size_t)h * LQ + i) * LQ + l + 64 * s] = f2bf(e[s] * rinv);
}

// ---------------- K4: o = attn @ V^T, fused gating, E written in-place over G ----------------
__global__ __launch_bounds__(256) void k_ogemm(
    const us* __restrict__ attn, const us* __restrict__ Vw, us* __restrict__ Gw)
{
  __shared__ __attribute__((aligned(16))) us AB[2][128 * 64];
  const int tid = threadIdx.x, w = tid >> 6, l = tid & 63;
  const int bx = blockIdx.x;
  // XCD grouping: 3 i0-siblings sharing a V-tile -> same bx%8
  const int xg = bx & 7, yg = bx >> 3;           // 1152 blocks: yg 0..143
  const int set = xg * 48 + yg / 3, i0 = (yg % 3) * 128;
  const int h = set / 96, n0 = (set % 96) * 128;
  const us* Ab = attn + (size_t)h * LQ * LQ;
  const us* Bb = Vw + (size_t)h * KDIM * LQ;
  f32x4 acc[4][4];
  #pragma unroll
  for (int mt = 0; mt < 4; ++mt)
    #pragma unroll
    for (int nt = 0; nt < 4; ++nt) acc[mt][nt] = (f32x4){0.f, 0.f, 0.f, 0.f};
  const int m0 = (w & 1) * 64, n0w = (w >> 1) * 64;
  const int row16 = l & 15, kq = l >> 4;
  for (int kk = 0; kk < 6; ++kk) {
    const int koff = kk * 64;
    #pragma unroll
    for (int s = 0; s < 4; ++s) {
      int slot = (s * 4 + w) * 64 + l;
      int rrow = slot >> 3, cc = slot & 7;
      int cg = cc ^ (rrow & 7);
      gl_lds16(Ab + (size_t)(i0 + rrow) * LQ + koff + cg * 8, &AB[0][slot * 8]);
      gl_lds16(Bb + (size_t)(n0 + rrow) * LQ + koff + cg * 8, &AB[1][slot * 8]);
    }
    asm volatile("s_waitcnt vmcnt(0)" ::: "memory");
    __syncthreads();
    #pragma unroll
    for (int kb = 0; kb < 2; ++kb) {
      bf16x8 af[4], bv[4];
      #pragma unroll
      for (int mt = 0; mt < 4; ++mt) {
        int r = m0 + mt * 16 + row16;
        int c = (kb * 4 + kq) ^ (r & 7);
        af[mt] = *(const bf16x8*)&AB[0][r * 64 + c * 8];
      }
      #pragma unroll
      for (int nt = 0; nt < 4; ++nt) {
        int r = n0w + nt * 16 + row16;
        int c = (kb * 4 + kq) ^ (r & 7);
        bv[nt] = *(const bf16x8*)&AB[1][r * 64 + c * 8];
      }
      #pragma unroll
      for (int mt = 0; mt < 4; ++mt)
        #pragma unroll
        for (int nt = 0; nt < 4; ++nt)
          acc[mt][nt] = __builtin_amdgcn_mfma_f32_16x16x32_bf16(af[mt], bv[nt], acc[mt][nt], 0, 0, 0);
    }
    __syncthreads();
  }
  // stage C (128x128 bf16 over both AB halves)
  us* C = &AB[0][0];
  #pragma unroll
  for (int mt = 0; mt < 4; ++mt)
    #pragma unroll
    for (int nt = 0; nt < 4; ++nt)
      #pragma unroll
      for (int v4 = 0; v4 < 4; ++v4)
        C[(m0 + mt * 16 + kq * 4 + v4) * 128 + n0w + nt * 16 + row16] = f2bf(acc[mt][nt][v4]);
  __syncthreads();
  // gated store: E[(i*384 + k)*128 + h*32 + d] = g * o, in-place over Gw
  const int k0 = n0 >> 5;
  #pragma unroll
  for (int it = 0; it < 8; ++it) {
    int slot = tid + 256 * it;      // 0..2047
    int xr = slot >> 4, ch = slot & 15;
    bf16x8 ov = *(const bf16x8*)&C[xr * 128 + ch * 8];
    size_t eaddr = ((size_t)(i0 + xr) * LQ + k0 + (ch >> 2)) * DPAIR + h * 32 + (ch & 3) * 8;
    bf16x8 gv = *(const bf16x8*)&Gw[eaddr];
    bf16x8 ev;
    #pragma unroll
    for (int q = 0; q < 8; ++q)
      ev[q] = (short)f2bf(bf2f((us)(unsigned short)ov[q]) * bf2f((us)(unsigned short)gv[q]));
    *(bf16x8*)&Gw[eaddr] = ev;
  }
}

// ---------------- K5: out[y,x,:] = E[x,y,:] @ Wo + bo ----------------
__global__ __launch_bounds__(256) void k_final(
    const us* __restrict__ E, const us* __restrict__ wt,
    const float* __restrict__ bo, float* __restrict__ out)
{
  __shared__ __attribute__((aligned(16))) us A[128 * 128];    // 32 KB
  const int tid = threadIdx.x, w = tid >> 6, l = tid & 63;
  const int y = blockIdx.x / 3, x0 = (blockIdx.x % 3) * 128;
  #pragma unroll
  for (int s4 = 0; s4 < 8; ++s4) {
    int slot = (s4 * 4 + w) * 64 + l;
    int r = slot >> 4, c = slot & 15, cg = c ^ (r & 7);
    gl_lds16(E + ((size_t)(x0 + r) * LQ + y) * DPAIR + cg * 8, &A[slot * 8]);
  }
  asm volatile("s_waitcnt vmcnt(0)" ::: "memory");
  __syncthreads();
  const us* W = wt + 4 * 16384;       // WoT
  const int m0 = (w & 1) * 64, n0w = (w >> 1) * 64;
  const int row16 = l & 15, kq = l >> 4;
  bf16x8 bv[4][4];
  #pragma unroll
  for (int nt = 0; nt < 4; ++nt)
    #pragma unroll
    for (int kb = 0; kb < 4; ++kb)
      bv[nt][kb] = *(const bf16x8*)&W[(n0w + nt * 16 + row16) * 128 + kb * 32 + kq * 8];
  f32x4 acc[4][4];
  #pragma unroll
  for (int mt = 0; mt < 4; ++mt)
    #pragma unroll
    for (int nt = 0; nt < 4; ++nt) acc[mt][nt] = (f32x4){0.f, 0.f, 0.f, 0.f};
  #pragma unroll
  for (int kb = 0; kb < 4; ++kb) {
    bf16x8 af[4];
    #pragma unroll
    for (int mt = 0; mt < 4; ++mt) {
      int r = m0 + mt * 16 + row16;
      int c = (kb * 4 + kq) ^ (r & 7);
      af[mt] = *(const bf16x8*)&A[r * 128 + c * 8];
    }
    #pragma unroll
    for (int mt = 0; mt < 4; ++mt)
      #pragma unroll
      for (int nt = 0; nt < 4; ++nt)
        acc[mt][nt] = __builtin_amdgcn_mfma_f32_16x16x32_bf16(af[mt], bv[nt][kb], acc[mt][nt], 0, 0, 0);
  }
  #pragma unroll
  for (int nt = 0; nt < 4; ++nt) {
    int n = n0w + nt * 16 + row16;
    float bov = bo[n];
    #pragma unroll
    for (int mt = 0; mt < 4; ++mt)
      #pragma unroll
      for (int v4 = 0; v4 < 4; ++v4) {
        int m = m0 + mt * 16 + kq * 4 + v4;
        out[((size_t)y * LQ + x0 + m) * DPAIR + n] = acc[mt][nt][v4] + bov;
      }
  }
}

extern "C" void kernel_launch(void* const* d_in, const int* in_sizes, int n_in,
                              void* d_out, int out_size, void* d_ws, size_t ws_size,
                              hipStream_t stream)
{
  const float* pair = (const float*)d_in[0];
  const float* bias = (const float*)d_in[1];
  const float* lng  = (const float*)d_in[2];
  const float* lnb  = (const float*)d_in[3];
  const float* Wq   = (const float*)d_in[4];
  const float* Wk   = (const float*)d_in[5];
  const float* Wv   = (const float*)d_in[6];
  const float* Wb   = (const float*)d_in[7];
  const float* Wg   = (const float*)d_in[8];
  const float* bg   = (const float*)d_in[9];
  const float* Wo   = (const float*)d_in[10];
  const float* bo   = (const float*)d_in[11];

  char* ws = (char*)d_ws;
  us* wt     = (us*)(ws + WT_OFF);
  us* Qw     = (us*)(ws + Q_OFF);
  us* Kw     = (us*)(ws + K_OFF);
  us* Vw     = (us*)(ws + V_OFF);
  us* Gw     = (us*)(ws + G_OFF);
  us* attn   = (us*)(ws + ATT_OFF);
  float* logits = (float*)(ws + LOG_OFF);

  k_pack<<<320, 256, 0, stream>>>(Wq, Wk, Wv, Wg, Wo, wt);
  k_lnqkvg<<<1152, 256, 0, stream>>>(pair, lng, lnb, bg, wt, Qw, Kw, Vw, Gw);
  hipMemsetAsync(logits, 0, (size_t)4 * LQ * LQ * 4, stream);
  k_logits<<<288, 256, 0, stream>>>(Qw, Kw, logits);
  k_softmax<<<384, 256, 0, stream>>>(bias, Wb, logits, attn);
  k_ogemm<<<1152, 256, 0, stream>>>(attn, Vw, Gw);
  k_final<<<1152, 256, 0, stream>>>(Gw, wt, bo, (float*)d_out);
}